// Round 8
// baseline (145.108 us; speedup 1.0000x reference)
//
#include <hip/hip_runtime.h>

// Problem constants
#define B_   8
#define TE_  256
#define TD_  256
#define D_   256
#define U_   256

// Workspace layout (float offsets). ~4.2 MB used.
#define EET_OFF   0        // (B, U/4, TE, 4) interleaved-transposed Ee
#define ED_OFF    524288   // (B, TD, U)  Ed = exp2(2log2e * de@w_de), row-major
#define MAXMU_OFF 1048576  // (B, TD)     row max of mu'
#define CNT_OFF   1050624  // 8 ints: per-b completion counters (K24 epilogue)

__device__ __forceinline__ float fexp2(float x) {
#if __has_builtin(__builtin_amdgcn_exp2f)
  return __builtin_amdgcn_exp2f(x);
#else
  return exp2f(x);
#endif
}
__device__ __forceinline__ float frcp(float x) {
#if __has_builtin(__builtin_amdgcn_rcpf)
  return __builtin_amdgcn_rcpf(x);
#else
  return 1.0f / x;
#endif
}

#define LOG2E_F 1.4426950408889634f
#define TWO_LOG2E_F 2.8853900817779268f

// ---------------------------------------------------------------------------
// K1 v4 (R6-identical + counter zeroing): 64 rows x 32 U-cols, 512 threads,
// 2x2 microtile, grid (8, 32, 2) = 512 blocks. W-panel staged to LDS once,
// barrier-free k-loop, A-loads lane-dedup'd. Block (0,0,0) zeroes the per-b
// counters used by K24's fused epilogue (runs before K24 in stream order, so
// every graph replay re-zeroes after the harness poison-fill).
// ---------------------------------------------------------------------------
__global__ __launch_bounds__(512) void coatt_k1_proj(
    const float* __restrict__ en, const float* __restrict__ de,
    const float* __restrict__ w_en, const float* __restrict__ w_de,
    float* __restrict__ eet, float* __restrict__ edp, int* __restrict__ cnt) {
  const int which = blockIdx.z;  // 0: en->EeT (interleaved), 1: de->Ed (direct)
  const float* __restrict__ A = which ? de : en;     // (2048, 256)
  const float* __restrict__ W = which ? w_de : w_en; // (256, 256)
  const int rowBase = blockIdx.y * 64;   // global row in (B*T)
  const int colBase = blockIdx.x * 32;   // col in U
  __shared__ float Bs[256][32];          // full-K W panel, 32KB
  const int tid = threadIdx.x;           // 0..511
  const int tx = tid & 15, ty = tid >> 4;  // cols tx*2.., rows ty*2.. (ty 0..31)

  if (which == 0 && blockIdx.x == 0 && blockIdx.y == 0 && tid < 8)
    cnt[tid] = 0;  // visible to K24 via kernel-boundary fence

  // Stage W panel once: thread (r = tid>>1, half = tid&1) loads 16 floats.
  {
    const int r = tid >> 1, h = (tid & 1) * 16;
#pragma unroll
    for (int j = 0; j < 4; ++j)
      *(float4*)&Bs[r][h + j * 4] =
          *(const float4*)&W[(size_t)r * U_ + colBase + h + j * 4];
  }
  __syncthreads();

  float acc[2][2] = {};
#pragma unroll 4
  for (int k4 = 0; k4 < 64; ++k4) {
    float a0[4], a1[4];
    *(float4*)a0 = *(const float4*)&A[(size_t)(rowBase + ty * 2 + 0) * D_ + k4 * 4];
    *(float4*)a1 = *(const float4*)&A[(size_t)(rowBase + ty * 2 + 1) * D_ + k4 * 4];
#pragma unroll
    for (int kk = 0; kk < 4; ++kk) {
      float b[2];
      *(float2*)b = *(const float2*)&Bs[k4 * 4 + kk][tx * 2];
      acc[0][0] = fmaf(a0[kk], b[0], acc[0][0]);
      acc[0][1] = fmaf(a0[kk], b[1], acc[0][1]);
      acc[1][0] = fmaf(a1[kk], b[0], acc[1][0]);
      acc[1][1] = fmaf(a1[kk], b[1], acc[1][1]);
    }
  }

  if (which) {
    // Ed: direct row-major float2 store (128B contiguous per ty-group).
#pragma unroll
    for (int i = 0; i < 2; ++i) {
      float2 o;
      o.x = fexp2(acc[i][0] * TWO_LOG2E_F);
      o.y = fexp2(acc[i][1] * TWO_LOG2E_F);
      *(float2*)&edp[(size_t)(rowBase + ty * 2 + i) * U_ + colBase + tx * 2] = o;
    }
  } else {
    // EeT interleaved: transpose via LDS (reuse Bs; need 32*69=2208 floats).
    __syncthreads();  // all ds_reads of Bs done before overwrite
    float* Cs = &Bs[0][0];
#pragma unroll
    for (int i = 0; i < 2; ++i)
#pragma unroll
      for (int j = 0; j < 2; ++j)
        Cs[(tx * 2 + j) * 69 + ty * 2 + i] = fexp2(acc[i][j] * TWO_LOG2E_F);
    __syncthreads();
    const int b = rowBase >> 8, t0 = rowBase & 255;
    const int u4Base = colBase >> 2;
    const int u4l = tid >> 6, tl = tid & 63;  // 8 u4-groups x 64 t
    float4 v;
    v.x = Cs[(u4l * 4 + 0) * 69 + tl];
    v.y = Cs[(u4l * 4 + 1) * 69 + tl];
    v.z = Cs[(u4l * 4 + 2) * 69 + tl];
    v.w = Cs[(u4l * 4 + 3) * 69 + tl];
    *(float4*)&eet[(size_t)((b * 64 + u4Base + u4l) * 256 + t0 + tl) * 4] = v;
  }
}

// ---------------------------------------------------------------------------
// K24 v3 (R6-identical main body) + fused K3 epilogue:
//   After a block finishes its 4 s-rows, it bumps cnt[b] (acq_rel, agent).
//   The LAST of b's 64 blocks (no spinning -- it's the last arriver) computes
//   softmax_s(maxmu[b,:]), h_hat[b,:], and writes out chunk 3 for all 256
//   s-rows of b. Removes the K3 launch + one ~10us stream boundary.
// grid 512, 512 threads.
// ---------------------------------------------------------------------------
__global__ __launch_bounds__(512) void coatt_k24(
    const float* __restrict__ en, const float* __restrict__ de,
    const float* __restrict__ nu, const float* __restrict__ eet,
    const float* __restrict__ edp, float* __restrict__ maxmu,
    int* __restrict__ cnt, float* __restrict__ out) {
  const int id = blockIdx.x;
  const int b = id & 7;             // XCD-aligned under round-robin dispatch
  const int sBase = (id >> 3) * 4;
  const int tid = threadIdx.x;      // 0..511
  const int t = tid & 255;
  const int half = tid >> 8;        // 0/1 -> local s rows {0,1} / {2,3}
  const int w = tid >> 6, lane = tid & 63;

  __shared__ float als[4][256];   // alphas (reused as max_alphas in epilogue)
  __shared__ float tp[2][4][256]; // t-phase partials [half][s][d]
  __shared__ float part[2][8];    // softmax partials
  __shared__ int lastFlag;

  // Wave-uniform Ed row base -> SGPR (readfirstlane). half is wave-uniform.
  const int edBase =
      __builtin_amdgcn_readfirstlane((b * TD_ + sBase + half * 2) * U_);
  const float* __restrict__ Ed0 = edp + edBase;        // uniform -> s_load
  const float* __restrict__ Ed1 = Ed0 + U_;
  const float* __restrict__ Ee_b = eet + (size_t)b * (U_ * TE_) + t * 4;

  float accA0 = 0.f, accB0 = 0.f, accA1 = 0.f, accB1 = 0.f;  // 2 chains per s
#pragma unroll 4
  for (int u4 = 0; u4 < 64; ++u4) {
    const float4 ee4 = *(const float4*)&Ee_b[u4 * 1024];  // coalesced 16B
    const float4 nv = *(const float4*)&nu[u4 * 4];        // uniform -> SGPR
    const float4 d0 = *(const float4*)&Ed0[u4 * 4];       // uniform -> SGPR
    const float4 d1 = *(const float4*)&Ed1[u4 * 4];       // uniform -> SGPR
    const float* eep = (const float*)&ee4;
    const float* nvp = (const float*)&nv;
    const float* p0 = (const float*)&d0;
    const float* p1 = (const float*)&d1;
#pragma unroll
    for (int j = 0; j < 4; ++j) {
      const float r0 = frcp(fmaf(p0[j], eep[j], 1.0f));
      const float r1 = frcp(fmaf(p1[j], eep[j], 1.0f));
      if (j & 1) {
        accB0 = fmaf(nvp[j], r0, accB0);
        accB1 = fmaf(nvp[j], r1, accB1);
      } else {
        accA0 = fmaf(nvp[j], r0, accA0);
        accA1 = fmaf(nvp[j], r1, accA1);
      }
    }
  }
  float v0 = -2.f * (accA0 + accB0);
  float v1 = -2.f * (accA1 + accB1);

  // Softmax over t for the 2 local s-rows; each covered by the half's 4 waves.
  float m0 = v0, m1 = v1;
#pragma unroll
  for (int off = 32; off > 0; off >>= 1) {
    m0 = fmaxf(m0, __shfl_xor(m0, off));
    m1 = fmaxf(m1, __shfl_xor(m1, off));
  }
  if (lane == 0) { part[0][w] = m0; part[1][w] = m1; }
  __syncthreads();
  const int wb = half * 4;
  m0 = fmaxf(fmaxf(part[0][wb], part[0][wb + 1]),
             fmaxf(part[0][wb + 2], part[0][wb + 3]));
  m1 = fmaxf(fmaxf(part[1][wb], part[1][wb + 1]),
             fmaxf(part[1][wb + 2], part[1][wb + 3]));
  __syncthreads();
  const float e0 = fexp2((v0 - m0) * LOG2E_F);
  const float e1 = fexp2((v1 - m1) * LOG2E_F);
  float sm0 = e0, sm1 = e1;
#pragma unroll
  for (int off = 32; off > 0; off >>= 1) {
    sm0 += __shfl_xor(sm0, off);
    sm1 += __shfl_xor(sm1, off);
  }
  if (lane == 0) { part[0][w] = sm0; part[1][w] = sm1; }
  __syncthreads();
  const float tot0 = (part[0][wb] + part[0][wb + 1]) +
                     (part[0][wb + 2] + part[0][wb + 3]);
  const float tot1 = (part[1][wb] + part[1][wb + 1]) +
                     (part[1][wb + 2] + part[1][wb + 3]);
  const int s0 = half * 2;
  als[s0][t] = e0 * frcp(tot0);
  als[s0 + 1][t] = e1 * frcp(tot1);
  if (t == 0) {
    maxmu[b * TD_ + sBase + s0] = m0;
    maxmu[b * TD_ + sBase + s0 + 1] = m1;
  }
  __syncthreads();

  // Phase t: d = t; halves cover disjoint t-ranges for ALL 4 s-rows.
  const int d = t;
  const int tBeg = half * 128;
  const float* __restrict__ en_b = en + (size_t)b * TE_ * D_ + d;
  float sa0 = 0.f, sa1 = 0.f, sa2 = 0.f, sa3 = 0.f;
#pragma unroll 4
  for (int t4 = 0; t4 < 32; ++t4) {
    const int tt = tBeg + t4 * 4;
    const float4 a0 = *(const float4*)&als[0][tt];  // LDS broadcast
    const float4 a1 = *(const float4*)&als[1][tt];
    const float4 a2 = *(const float4*)&als[2][tt];
    const float4 a3 = *(const float4*)&als[3][tt];
    float env[4];
#pragma unroll
    for (int j = 0; j < 4; ++j) env[j] = en_b[(size_t)(tt + j) * D_];  // coalesced
    const float* q0 = (const float*)&a0;
    const float* q1 = (const float*)&a1;
    const float* q2 = (const float*)&a2;
    const float* q3 = (const float*)&a3;
#pragma unroll
    for (int j = 0; j < 4; ++j) {
      sa0 = fmaf(q0[j], env[j], sa0);
      sa1 = fmaf(q1[j], env[j], sa1);
      sa2 = fmaf(q2[j], env[j], sa2);
      sa3 = fmaf(q3[j], env[j], sa3);
    }
  }
  tp[half][0][d] = sa0;
  tp[half][1][d] = sa1;
  tp[half][2][d] = sa2;
  tp[half][3][d] = sa3;
  __syncthreads();
#pragma unroll
  for (int k = 0; k < 2; ++k) {
    const int sl = s0 + k;
    const float se = tp[0][sl][d] + tp[1][sl][d];
    const int s = sBase + sl;
    const float dd = de[(size_t)(b * TD_ + s) * D_ + d];
    float* o = out + (size_t)(b * TD_ + s) * (4 * D_);
    o[d] = dd;
    o[D_ + d] = se;
    o[2 * D_ + d] = dd * se;
  }

  // ---- Fused K3 epilogue: last block of this b does the cross-block work ----
  if (tid == 0) {
    __threadfence();  // make this block's maxmu writes agent-visible
    const int old = __hip_atomic_fetch_add(&cnt[b], 1, __ATOMIC_ACQ_REL,
                                           __HIP_MEMORY_SCOPE_AGENT);
    lastFlag = (old == 63);
  }
  __syncthreads();
  if (lastFlag) {
    __threadfence();  // acquire side: all 64 blocks' maxmu visible
    float* ma = als[0];  // reuse LDS (256 floats)
    // softmax over maxmu[b,:]: all 512 threads, values duplicated across
    // halves (max unaffected; sum corrected by 0.5).
    const float vv = maxmu[b * TD_ + t];
    float m2 = vv;
#pragma unroll
    for (int off = 32; off > 0; off >>= 1) m2 = fmaxf(m2, __shfl_xor(m2, off));
    if (lane == 0) part[0][w] = m2;
    __syncthreads();
    m2 = fmaxf(fmaxf(fmaxf(part[0][0], part[0][1]), fmaxf(part[0][2], part[0][3])),
               fmaxf(fmaxf(part[0][4], part[0][5]), fmaxf(part[0][6], part[0][7])));
    const float e2 = fexp2((vv - m2) * LOG2E_F);
    float sm2 = e2;
#pragma unroll
    for (int off = 32; off > 0; off >>= 1) sm2 += __shfl_xor(sm2, off);
    if (lane == 0) part[1][w] = sm2;
    __syncthreads();
    const float tot2 = 0.5f * (((part[1][0] + part[1][1]) + (part[1][2] + part[1][3])) +
                               ((part[1][4] + part[1][5]) + (part[1][6] + part[1][7])));
    ma[t] = e2 * frcp(tot2);  // halves write identical values
    __syncthreads();
    // h_hat[b, d=t]: halves split the s-range; combine via tp.
    const float* __restrict__ de_b = de + (size_t)b * TD_ * D_ + t;
    float acc = 0.f;
#pragma unroll 4
    for (int s = half * 128; s < half * 128 + 128; ++s)
      acc = fmaf(de_b[(size_t)s * D_], ma[s], acc);
    tp[half][0][t] = acc;
    __syncthreads();
    const float hh = tp[0][0][t] + tp[1][0][t];
    // out chunk 3 for all 256 s-rows of b (halves split the s-range).
#pragma unroll 4
    for (int s = half * 128; s < half * 128 + 128; ++s) {
      const float dd = de_b[(size_t)s * D_];
      out[(size_t)(b * TD_ + s) * (4 * D_) + 3 * D_ + t] = dd * hh;
    }
  }
}

extern "C" void kernel_launch(void* const* d_in, const int* in_sizes, int n_in,
                              void* d_out, int out_size, void* d_ws, size_t ws_size,
                              hipStream_t stream) {
  (void)in_sizes; (void)n_in; (void)out_size; (void)ws_size;
  const float* en   = (const float*)d_in[0];
  const float* de   = (const float*)d_in[1];
  const float* w_en = (const float*)d_in[2];
  const float* w_de = (const float*)d_in[3];
  const float* nu   = (const float*)d_in[4];
  float* out = (float*)d_out;
  float* ws  = (float*)d_ws;
  int* cnt = (int*)(ws + CNT_OFF);

  coatt_k1_proj<<<dim3(8, 32, 2), 512, 0, stream>>>(
      en, de, w_en, w_de, ws + EET_OFF, ws + ED_OFF, cnt);
  coatt_k24<<<dim3(512), 512, 0, stream>>>(
      en, de, nu, ws + EET_OFF, ws + ED_OFF, ws + MAXMU_OFF, cnt, out);
}

// Round 10
// 112.327 us; speedup vs baseline: 1.2918x; 1.2918x over previous
//
#include <hip/hip_runtime.h>

// Problem constants
#define B_   8
#define TE_  256
#define TD_  256
#define D_   256
#define U_   256

// Workspace layout (float offsets). ~4.2 MB used.
#define EET_OFF   0        // (B, U/4, TE, 4) interleaved-transposed Ee
#define ED_OFF    524288   // (B, TD, U)  Ed = exp2(2log2e * de@w_de), row-major
#define MAXMU_OFF 1048576  // (B, TD)     row max of mu'

__device__ __forceinline__ float fexp2(float x) {
#if __has_builtin(__builtin_amdgcn_exp2f)
  return __builtin_amdgcn_exp2f(x);
#else
  return exp2f(x);
#endif
}
__device__ __forceinline__ float frcp(float x) {
#if __has_builtin(__builtin_amdgcn_rcpf)
  return __builtin_amdgcn_rcpf(x);
#else
  return 1.0f / x;
#endif
}

#define LOG2E_F 1.4426950408889634f
#define TWO_LOG2E_F 2.8853900817779268f

// ---------------------------------------------------------------------------
// K1 v4 (R6-identical): 64 rows x 32 U-cols, 512 threads, 2x2 microtile,
// grid (8, 32, 2) = 512 blocks -> 2 blocks/CU, 4 waves/SIMD. W-panel staged
// to LDS once, barrier-free k-loop, A-loads lane-dedup'd. Measured ~11 us.
// ---------------------------------------------------------------------------
__global__ __launch_bounds__(512) void coatt_k1_proj(
    const float* __restrict__ en, const float* __restrict__ de,
    const float* __restrict__ w_en, const float* __restrict__ w_de,
    float* __restrict__ eet, float* __restrict__ edp) {
  const int which = blockIdx.z;  // 0: en->EeT (interleaved), 1: de->Ed (direct)
  const float* __restrict__ A = which ? de : en;     // (2048, 256)
  const float* __restrict__ W = which ? w_de : w_en; // (256, 256)
  const int rowBase = blockIdx.y * 64;   // global row in (B*T)
  const int colBase = blockIdx.x * 32;   // col in U
  __shared__ float Bs[256][32];          // full-K W panel, 32KB
  const int tid = threadIdx.x;           // 0..511
  const int tx = tid & 15, ty = tid >> 4;  // cols tx*2.., rows ty*2.. (ty 0..31)

  // Stage W panel once: thread (r = tid>>1, half = tid&1) loads 16 floats.
  {
    const int r = tid >> 1, h = (tid & 1) * 16;
#pragma unroll
    for (int j = 0; j < 4; ++j)
      *(float4*)&Bs[r][h + j * 4] =
          *(const float4*)&W[(size_t)r * U_ + colBase + h + j * 4];
  }
  __syncthreads();

  float acc[2][2] = {};
#pragma unroll 4
  for (int k4 = 0; k4 < 64; ++k4) {
    float a0[4], a1[4];
    *(float4*)a0 = *(const float4*)&A[(size_t)(rowBase + ty * 2 + 0) * D_ + k4 * 4];
    *(float4*)a1 = *(const float4*)&A[(size_t)(rowBase + ty * 2 + 1) * D_ + k4 * 4];
#pragma unroll
    for (int kk = 0; kk < 4; ++kk) {
      float b[2];
      *(float2*)b = *(const float2*)&Bs[k4 * 4 + kk][tx * 2];
      acc[0][0] = fmaf(a0[kk], b[0], acc[0][0]);
      acc[0][1] = fmaf(a0[kk], b[1], acc[0][1]);
      acc[1][0] = fmaf(a1[kk], b[0], acc[1][0]);
      acc[1][1] = fmaf(a1[kk], b[1], acc[1][1]);
    }
  }

  if (which) {
    // Ed: direct row-major float2 store (128B contiguous per ty-group).
#pragma unroll
    for (int i = 0; i < 2; ++i) {
      float2 o;
      o.x = fexp2(acc[i][0] * TWO_LOG2E_F);
      o.y = fexp2(acc[i][1] * TWO_LOG2E_F);
      *(float2*)&edp[(size_t)(rowBase + ty * 2 + i) * U_ + colBase + tx * 2] = o;
    }
  } else {
    // EeT interleaved: transpose via LDS (reuse Bs; need 32*69=2208 floats).
    __syncthreads();  // all ds_reads of Bs done before overwrite
    float* Cs = &Bs[0][0];
#pragma unroll
    for (int i = 0; i < 2; ++i)
#pragma unroll
      for (int j = 0; j < 2; ++j)
        Cs[(tx * 2 + j) * 69 + ty * 2 + i] = fexp2(acc[i][j] * TWO_LOG2E_F);
    __syncthreads();
    const int b = rowBase >> 8, t0 = rowBase & 255;
    const int u4Base = colBase >> 2;
    const int u4l = tid >> 6, tl = tid & 63;  // 8 u4-groups x 64 t
    float4 v;
    v.x = Cs[(u4l * 4 + 0) * 69 + tl];
    v.y = Cs[(u4l * 4 + 1) * 69 + tl];
    v.z = Cs[(u4l * 4 + 2) * 69 + tl];
    v.w = Cs[(u4l * 4 + 3) * 69 + tl];
    *(float4*)&eet[(size_t)((b * 64 + u4Base + u4l) * 256 + t0 + tl) * 4] = v;
  }
}

// ---------------------------------------------------------------------------
// K24 (fused K2+K4): the R2 LDS-preload variant -- the version A/B-measured
// at ~20 us/launch in R4. Ed rows + nu preloaded to LDS once; u-loop
// operands are broadcast ds_read_b128 (pipelined, conflict-free) -- NOT
// s_load (SMEM returns out-of-order, forcing lgkmcnt(0) drains ~300cy per
// unroll group; R8 measured that variant at ~40 us, VALUBusy 25%).
// 512 threads, grid 512; b = id&7 XCD-aligned.
// ---------------------------------------------------------------------------
__global__ __launch_bounds__(512) void coatt_k24(
    const float* __restrict__ en, const float* __restrict__ de,
    const float* __restrict__ nu, const float* __restrict__ eet,
    const float* __restrict__ edp, float* __restrict__ maxmu,
    float* __restrict__ out) {
  const int id = blockIdx.x;
  const int b = id & 7;             // XCD-aligned under round-robin dispatch
  const int sBase = (id >> 3) * 4;
  const int tid = threadIdx.x;      // 0..511
  const int t = tid & 255;
  const int half = tid >> 8;        // 0/1 -> local s rows {0,1} / {2,3}
  const int w = tid >> 6, lane = tid & 63;

  __shared__ float eds[4][256];   // 4 Ed rows
  __shared__ float nus[256];
  __shared__ float als[4][256];   // alphas
  __shared__ float tp[2][4][256]; // t-phase partials [half][s][d]
  __shared__ float part[2][8];    // softmax partials [s-local-in-half][wave]

  // Preload Ed rows + nu into LDS (coalesced float2).
  {
    const float2* src = (const float2*)(edp + (size_t)(b * TD_ + sBase) * U_);
    ((float2*)&eds[0][0])[tid] = src[tid];  // 512 float2 = 1024 floats
    if (tid < 128) ((float2*)nus)[tid] = ((const float2*)nu)[tid];
  }
  __syncthreads();

  const float* __restrict__ Ee_b = eet + (size_t)b * (U_ * TE_) + t * 4;
  const int s0 = half * 2;
  float accA0 = 0.f, accB0 = 0.f, accA1 = 0.f, accB1 = 0.f;  // 2 chains per s
#pragma unroll 4
  for (int u4 = 0; u4 < 64; ++u4) {
    const float4 ee4 = *(const float4*)&Ee_b[u4 * 1024];  // coalesced 16B
    const float4 nv = *(const float4*)&nus[u4 * 4];       // LDS broadcast
    const float4 d0 = *(const float4*)&eds[s0][u4 * 4];
    const float4 d1 = *(const float4*)&eds[s0 + 1][u4 * 4];
    const float* eep = (const float*)&ee4;
    const float* nvp = (const float*)&nv;
    const float* p0 = (const float*)&d0;
    const float* p1 = (const float*)&d1;
#pragma unroll
    for (int j = 0; j < 4; ++j) {
      const float r0 = frcp(fmaf(p0[j], eep[j], 1.0f));
      const float r1 = frcp(fmaf(p1[j], eep[j], 1.0f));
      if (j & 1) {
        accB0 = fmaf(nvp[j], r0, accB0);
        accB1 = fmaf(nvp[j], r1, accB1);
      } else {
        accA0 = fmaf(nvp[j], r0, accA0);
        accA1 = fmaf(nvp[j], r1, accA1);
      }
    }
  }
  float v0 = -2.f * (accA0 + accB0);
  float v1 = -2.f * (accA1 + accB1);

  // Softmax over t for the 2 local s-rows; each covered by the half's 4 waves.
  float m0 = v0, m1 = v1;
#pragma unroll
  for (int off = 32; off > 0; off >>= 1) {
    m0 = fmaxf(m0, __shfl_xor(m0, off));
    m1 = fmaxf(m1, __shfl_xor(m1, off));
  }
  if (lane == 0) { part[0][w] = m0; part[1][w] = m1; }
  __syncthreads();
  const int wb = half * 4;
  m0 = fmaxf(fmaxf(part[0][wb], part[0][wb + 1]),
             fmaxf(part[0][wb + 2], part[0][wb + 3]));
  m1 = fmaxf(fmaxf(part[1][wb], part[1][wb + 1]),
             fmaxf(part[1][wb + 2], part[1][wb + 3]));
  __syncthreads();
  const float e0 = fexp2((v0 - m0) * LOG2E_F);
  const float e1 = fexp2((v1 - m1) * LOG2E_F);
  float sm0 = e0, sm1 = e1;
#pragma unroll
  for (int off = 32; off > 0; off >>= 1) {
    sm0 += __shfl_xor(sm0, off);
    sm1 += __shfl_xor(sm1, off);
  }
  if (lane == 0) { part[0][w] = sm0; part[1][w] = sm1; }
  __syncthreads();
  const float tot0 = (part[0][wb] + part[0][wb + 1]) +
                     (part[0][wb + 2] + part[0][wb + 3]);
  const float tot1 = (part[1][wb] + part[1][wb + 1]) +
                     (part[1][wb + 2] + part[1][wb + 3]);
  als[s0][t] = e0 * frcp(tot0);
  als[s0 + 1][t] = e1 * frcp(tot1);
  if (t == 0) {
    maxmu[b * TD_ + sBase + s0] = m0;
    maxmu[b * TD_ + sBase + s0 + 1] = m1;
  }
  __syncthreads();

  // Phase t: d = t; halves cover disjoint t-ranges for ALL 4 s-rows.
  const int d = t;
  const int tBeg = half * 128;
  const float* __restrict__ en_b = en + (size_t)b * TE_ * D_ + d;
  float sa0 = 0.f, sa1 = 0.f, sa2 = 0.f, sa3 = 0.f;
#pragma unroll 4
  for (int t4 = 0; t4 < 32; ++t4) {
    const int tt = tBeg + t4 * 4;
    const float4 a0 = *(const float4*)&als[0][tt];  // LDS broadcast
    const float4 a1 = *(const float4*)&als[1][tt];
    const float4 a2 = *(const float4*)&als[2][tt];
    const float4 a3 = *(const float4*)&als[3][tt];
    float env[4];
#pragma unroll
    for (int j = 0; j < 4; ++j) env[j] = en_b[(size_t)(tt + j) * D_];  // coalesced
    const float* q0 = (const float*)&a0;
    const float* q1 = (const float*)&a1;
    const float* q2 = (const float*)&a2;
    const float* q3 = (const float*)&a3;
#pragma unroll
    for (int j = 0; j < 4; ++j) {
      sa0 = fmaf(q0[j], env[j], sa0);
      sa1 = fmaf(q1[j], env[j], sa1);
      sa2 = fmaf(q2[j], env[j], sa2);
      sa3 = fmaf(q3[j], env[j], sa3);
    }
  }
  tp[half][0][d] = sa0;
  tp[half][1][d] = sa1;
  tp[half][2][d] = sa2;
  tp[half][3][d] = sa3;
  __syncthreads();
#pragma unroll
  for (int k = 0; k < 2; ++k) {
    const int sl = s0 + k;
    const float se = tp[0][sl][d] + tp[1][sl][d];
    const int s = sBase + sl;
    const float dd = de[(size_t)(b * TD_ + s) * D_ + d];
    float* o = out + (size_t)(b * TD_ + s) * (4 * D_);
    o[d] = dd;
    o[D_ + d] = se;
    o[2 * D_ + d] = dd * se;
  }
}

// ---------------------------------------------------------------------------
// K3 (R6-identical): max_alphas = softmax_s(maxmu[b,:]); h_hat; out chunk 3.
// grid (8, 8), 256 threads. Measured ~3 us; the R8 fused-epilogue version
// cost ~30 us of 8-block tail -- separate kernel wins.
// ---------------------------------------------------------------------------
__global__ __launch_bounds__(256) void coatt_k3_hhat(
    const float* __restrict__ de, const float* __restrict__ maxmu,
    float* __restrict__ out) {
  const int b = blockIdx.y;
  const int dBase = blockIdx.x * 32;
  const int tid = threadIdx.x;
  const int w = tid >> 6, lane = tid & 63;
  __shared__ float red[8];
  __shared__ float malpha[256];
  __shared__ float acc_red[256];
  __shared__ float hh_s[32];
  const float vv = maxmu[b * TD_ + tid];
  float m = vv;
#pragma unroll
  for (int off = 32; off > 0; off >>= 1) m = fmaxf(m, __shfl_xor(m, off));
  if (lane == 0) red[w] = m;
  __syncthreads();
  m = fmaxf(fmaxf(red[0], red[1]), fmaxf(red[2], red[3]));
  const float e = fexp2((vv - m) * LOG2E_F);
  float sm = e;
#pragma unroll
  for (int off = 32; off > 0; off >>= 1) sm += __shfl_xor(sm, off);
  if (lane == 0) red[4 + w] = sm;
  __syncthreads();
  sm = (red[4] + red[5]) + (red[6] + red[7]);
  malpha[tid] = e * frcp(sm);
  __syncthreads();
  const int dl = tid & 31, sg = tid >> 5;
  float acc = 0.f;
  for (int s = sg * 32; s < sg * 32 + 32; ++s)
    acc = fmaf(de[(size_t)(b * TD_ + s) * D_ + dBase + dl], malpha[s], acc);
  acc_red[tid] = acc;
  __syncthreads();
  if (tid < 32) {
    float tsum = acc_red[tid];
#pragma unroll
    for (int g = 1; g < 8; ++g) tsum += acc_red[g * 32 + tid];
    hh_s[tid] = tsum;
  }
  __syncthreads();
  const float hh = hh_s[dl];
#pragma unroll 4
  for (int s = sg; s < TD_; s += 8) {
    const float dd = de[(size_t)(b * TD_ + s) * D_ + dBase + dl];
    out[(size_t)(b * TD_ + s) * (4 * D_) + 3 * D_ + dBase + dl] = dd * hh;
  }
}

extern "C" void kernel_launch(void* const* d_in, const int* in_sizes, int n_in,
                              void* d_out, int out_size, void* d_ws, size_t ws_size,
                              hipStream_t stream) {
  (void)in_sizes; (void)n_in; (void)out_size; (void)ws_size;
  const float* en   = (const float*)d_in[0];
  const float* de   = (const float*)d_in[1];
  const float* w_en = (const float*)d_in[2];
  const float* w_de = (const float*)d_in[3];
  const float* nu   = (const float*)d_in[4];
  float* out = (float*)d_out;
  float* ws  = (float*)d_ws;

  coatt_k1_proj<<<dim3(8, 32, 2), 512, 0, stream>>>(
      en, de, w_en, w_de, ws + EET_OFF, ws + ED_OFF);
  coatt_k24<<<dim3(512), 512, 0, stream>>>(
      en, de, nu, ws + EET_OFF, ws + ED_OFF, ws + MAXMU_OFF, out);
  coatt_k3_hhat<<<dim3(8, 8), 256, 0, stream>>>(de, ws + MAXMU_OFF, out);
}